// Round 16
// baseline (2312.672 us; speedup 1.0000x reference)
//
#include <hip/hip_runtime.h>
#include <hip/hip_bf16.h>

// ============================================================================
// EpisodeMultiheadAttentionBlock — round 16.
// r15 (best: 768 µs) + causal-skip in k_attn with INTERLEAVED work assignment:
//  * QK granules (16-wide) assigned g%8==wv -> per-wave count (gmax-wv)/8+1
//    (avg 6.5 vs 8); fully-masked pad granules filled with -1e30 (no MFMA).
//  * softmax + P-write + macc bounded to nchunks=ceil((36+qt)/4) chunks
//    (avg 12.1 vs 16) — bit-exact (masked entries were exp->0 = +0.0).
//  * PV slices interleaved by parity across halves; nchunks slices/half.
//  All loops fixed-trip + uniform guard (static reg indices; no rule-#20 trap).
//  Everything outside k_attn byte-identical to r15.
// ============================================================================

typedef __attribute__((ext_vector_type(8))) short bf16x8;
typedef __attribute__((ext_vector_type(4))) float f32x4;

__device__ __forceinline__ short f2bs(float f) {
  union { __hip_bfloat16 h; short s; } u; u.h = __float2bfloat16(f); return u.s;
}

// ---------------- workspace layout (bytes); peak 192,446,464 ---------------
static constexpr size_t OFF_WT   = 0;            // 10 x 1M bf16 W^T (20,971,520)
static constexpr size_t OFF_TAB  = 20971520;     // f32 (cos,sin) 5000x512x2 (20,480,000)
static constexpr size_t OFF_XBF  = 41451520;     // bf16 x [16384][1024] (33,554,432)
static constexpr size_t OFF_QH   = 75005952;     // qh bf16 [b,h][512][64] (16,777,216)
static constexpr size_t OFF_KH   = 91783168;     // kh bf16 [b,h][1024][64] (33,554,432)
static constexpr size_t OFF_VT   = 125337600;    // vT bf16 [b,h][64][1024] (33,554,432)
static constexpr size_t OFF_OAT  = 158892032;    // attn-out bf16 (16,777,216)
static constexpr size_t OFF_O2   = 175669248;    // o2 bf16 (16,777,216) -> 192,446,464
// overlays (lifetimes audited against launch order):
static constexpr size_t OFF_INV  = OFF_OAT;      // f64 inv[512] (4KB); dead before oat
static constexpr size_t OFF_RBZB = 75005952;     // f32 [8192][2048] (67,108,864) post-attn
static constexpr size_t OFF_RX   = 142114816;    // rx bf16 (16,777,216) over dead vt-tail
static constexpr size_t OFF_HB   = OFF_XBF;      // Hb f32 (33,554,432) over dead xbf

// swizzle for the 16x1024 S/P tile: spreads 64 lanes over all 32 banks.
__device__ __forceinline__ int swz(int q) { return ((q & 3) << 3) ^ ((q & 12) << 2); }

// ---------------- x: f32 -> bf16 ------------------------------------------
__global__ __launch_bounds__(256) void k_cvtx(const float* __restrict__ x,
                                              short* __restrict__ xbf) {
  size_t i = ((size_t)blockIdx.x * 256 + threadIdx.x) * 8;
  f32x4 a = *(const f32x4*)(x + i);
  f32x4 b = *(const f32x4*)(x + i + 4);
  bf16x8 o;
  o[0] = f2bs(a[0]); o[1] = f2bs(a[1]); o[2] = f2bs(a[2]); o[3] = f2bs(a[3]);
  o[4] = f2bs(b[0]); o[5] = f2bs(b[1]); o[6] = f2bs(b[2]); o[7] = f2bs(b[3]);
  *(bf16x8*)(xbf + i) = o;
}

// ---------------- rope table: inv hoisted (f64), then sincos ---------------
__global__ void k_tabinv(double* __restrict__ inv) {
  int i = threadIdx.x;  // 512 threads, 1 block
  inv[i] = pow(10000.0, -(double)i / 512.0);
}
__global__ __launch_bounds__(256) void k_table(float* __restrict__ tab,
                                               const double* __restrict__ inv) {
  int i = blockIdx.x * 256 + threadIdx.x;
  if (i >= 5000 * 512) return;
  int pos = i >> 9, fi = i & 511;
  double ds, dc;
  sincos((double)pos * inv[fi], &ds, &dc);
  tab[2 * i] = (float)dc;
  tab[2 * i + 1] = (float)ds;
}

// ---------------- weight transpose: W[k][n] f32 -> Wt[n][k] bf16 -----------
struct W10 { const float* p[10]; };
__global__ __launch_bounds__(256) void k_wt(W10 wsrc, short* __restrict__ wt) {
  __shared__ short t[32][33];
  int kb = blockIdx.x * 32, nb = blockIdx.y * 32, wi = blockIdx.z;
  const float* src = wsrc.p[wi];
  int tid = threadIdx.x;
#pragma unroll
  for (int e = 0; e < 4; ++e) {
    int idx = e * 256 + tid;
    int kr = idx >> 5, nc = idx & 31;
    t[nc][kr] = f2bs(src[(size_t)(kb + kr) * 1024 + nb + nc]);
  }
  __syncthreads();
  short* dst = wt + (size_t)wi * 1024 * 1024;
#pragma unroll
  for (int e = 0; e < 4; ++e) {
    int idx = e * 256 + tid;
    int nr = idx >> 5, kc = idx & 31;
    dst[(size_t)(nb + nr) * 1024 + kb + kc] = t[nr][kc];
  }
}

// ---------------- generic 128x128 MFMA GEMM, templated epilogue ------------
enum { CM_BF16 = 0, CM_F32 = 2, CM_F32ACC = 3, CM_VT = 4, CM_ROPE = 5 };

template <int AMODE, int CMODE>
__global__ __launch_bounds__(256) void k_gemm(
    const short* __restrict__ A, const short* __restrict__ Bt,
    const float* __restrict__ bias, const float* __restrict__ bias2,
    void* __restrict__ Cout, int ldc,
    const float* __restrict__ tab, const int* __restrict__ kidx,
    int sshift, int qoff) {
  __shared__ __align__(16) short lA[128 * 32];
  __shared__ __align__(16) short lB[128 * 32];
  const int tid = threadIdx.x;
  const int lane = tid & 63;
  const int wv = tid >> 6;
  const int wm = wv >> 1, wn = wv & 1;
  const int lo = lane & 15, hi = lane >> 4;
  const int tm0 = blockIdx.x * 128;
  const int tn0 = blockIdx.y * 128;

  const f32x4 vz = {0.f, 0.f, 0.f, 0.f};
  f32x4 acc[4][4];
#pragma unroll
  for (int m = 0; m < 4; ++m)
#pragma unroll
    for (int n = 0; n < 4; ++n) acc[m][n] = vz;

  for (int kt = 0; kt < 32; ++kt) {
    const int k0 = kt * 32;
    __syncthreads();
#pragma unroll
    for (int i = 0; i < 2; ++i) {
      int f = i * 256 + tid;
      int r = f >> 2;
      int cb = (f & 3) * 16;
      int arow = tm0 + r;
      if (AMODE) arow = ((arow >> 9) << 10) + 512 + (arow & 511);
      const char* ga = (const char*)(A + (size_t)arow * 1024 + k0) + cb;
      __builtin_amdgcn_global_load_lds(
          (const __attribute__((address_space(1))) void*)ga,
          (__attribute__((address_space(3))) void*)((char*)lA + (size_t)(i * 256 + wv * 64) * 16),
          16, 0, 0);
      int brow = tn0 + r;
      const char* gb = (const char*)(Bt + (size_t)brow * 1024 + k0) + cb;
      __builtin_amdgcn_global_load_lds(
          (const __attribute__((address_space(1))) void*)gb,
          (__attribute__((address_space(3))) void*)((char*)lB + (size_t)(i * 256 + wv * 64) * 16),
          16, 0, 0);
    }
    __syncthreads();
    bf16x8 af[4], bfr[4];
#pragma unroll
    for (int m = 0; m < 4; ++m)
      af[m] = *(const bf16x8*)&lA[(wm * 64 + m * 16 + lo) * 32 + hi * 8];
#pragma unroll
    for (int n = 0; n < 4; ++n)
      bfr[n] = *(const bf16x8*)&lB[(wn * 64 + n * 16 + lo) * 32 + hi * 8];
#pragma unroll
    for (int m = 0; m < 4; ++m)
#pragma unroll
      for (int n = 0; n < 4; ++n)
        acc[m][n] = __builtin_amdgcn_mfma_f32_16x16x32_bf16(af[m], bfr[n], acc[m][n], 0, 0, 0);
  }

  if constexpr (CMODE == CM_ROPE) {
    __hip_bfloat16* out = (__hip_bfloat16*)Cout;
    const float2* t2 = (const float2*)tab;
    const int srows = 1 << sshift;
    const float sgn = (lane & 1) ? 1.f : -1.f;
#pragma unroll
    for (int m = 0; m < 4; ++m) {
      int row_base = tm0 + wm * 64 + m * 16 + hi * 4;
#pragma unroll
      for (int n = 0; n < 4; ++n) {
        int col = tn0 + wn * 64 + n * 16 + lo;
        float bsv = bias[col];
        int j = col >> 1, hh = col >> 6, dd = col & 63;
#pragma unroll
        for (int r = 0; r < 4; ++r) {
          int row = row_base + r;
          int bb = row >> sshift, ss = row & (srows - 1);
          int idx = kidx[bb * 1024 + qoff + ss];
          float2 cs = t2[(size_t)idx * 512 + j];
          float val = acc[m][n][r] + bsv;
          float part = __shfl_xor(val, 1);
          float rot = val * cs.x + sgn * part * cs.y;
          out[((size_t)(bb * 16 + hh) * srows + ss) * 64 + dd] = __float2bfloat16(rot);
        }
      }
    }
  } else if constexpr (CMODE == CM_VT) {
    __hip_bfloat16* out = (__hip_bfloat16*)Cout;
#pragma unroll
    for (int m = 0; m < 4; ++m) {
      int row_base = tm0 + wm * 64 + m * 16 + hi * 4;
#pragma unroll
      for (int n = 0; n < 4; ++n) {
        int col = tn0 + wn * 64 + n * 16 + lo;
        float bsv = bias[col];
        int hh = col >> 6, dd = col & 63;
#pragma unroll
        for (int r = 0; r < 4; ++r) {
          int row = row_base + r;
          int bb = row >> 10, ss = row & 1023;
          out[((size_t)(bb * 16 + hh) * 64 + dd) * 1024 + ss] =
              __float2bfloat16(acc[m][n][r] + bsv);
        }
      }
    }
  } else if constexpr (CMODE == CM_F32 || CMODE == CM_F32ACC) {
    float* out = (float*)Cout;
#pragma unroll
    for (int m = 0; m < 4; ++m) {
      int row_base = tm0 + wm * 64 + m * 16 + hi * 4;
#pragma unroll
      for (int n = 0; n < 4; ++n) {
        int col = tn0 + wn * 64 + n * 16 + lo;
        float bsv = (col < 1024 || !bias2) ? bias[col] : bias2[col - 1024];
#pragma unroll
        for (int r = 0; r < 4; ++r) {
          size_t off = (size_t)(row_base + r) * ldc + col;
          float val = acc[m][n][r] + bsv;
          if constexpr (CMODE == CM_F32ACC) val += out[off];
          out[off] = val;
        }
      }
    }
  } else {
    __hip_bfloat16* out = (__hip_bfloat16*)Cout;
#pragma unroll
    for (int m = 0; m < 4; ++m) {
      int row_base = tm0 + wm * 64 + m * 16 + hi * 4;
#pragma unroll
      for (int n = 0; n < 4; ++n) {
        int col = tn0 + wn * 64 + n * 16 + lo;
        float bsv = bias[col];
#pragma unroll
        for (int r = 0; r < 4; ++r) {
          size_t off = (size_t)(row_base + r) * ldc + col;
          out[off] = __float2bfloat16(acc[m][n][r] + bsv);
        }
      }
    }
  }
}

// ---------------- attention v9: r15/r10 structure + causal skip ------------
// 1D grid 512 (wgid = qt*16 + b => XCD = b%8). 512 thr / 8 waves.
// Valid K granules (16-wide): g <= gmax = 32+qt. Interleaved ownership
// (g%8==wv) distributes skip savings across ALL waves (critical path).
__global__ __launch_bounds__(512, 2) void k_attn(
    const __hip_bfloat16* __restrict__ qh,
    const __hip_bfloat16* __restrict__ kh,
    const __hip_bfloat16* __restrict__ vt,
    const unsigned char* __restrict__ padraw,
    float* __restrict__ mean_out,
    __hip_bfloat16* __restrict__ oat) {
  __shared__ float Sld[16 * 1024];     // 64 KiB; bf16 P overlays row second halves
  __shared__ float osc[4 * 64 * 4];    // 4 KiB PV combine scratch
  short* Pld = (short*)Sld;
  const int wgid = blockIdx.x;
  const int b = wgid & 15, qt = wgid >> 4;
  const int tid = threadIdx.x, lane = tid & 63, wv = tid >> 6;
  const int lo = lane & 15, hi = lane >> 4;
  const int wg = wv & 3, half = wv >> 2;
  const f32x4 vz = {0.f, 0.f, 0.f, 0.f};

  // causal geometry: last valid granule, chunk count, pad boundary
  const int gmax = 32 + qt;                 // granule = 16 kpos
  const int nchunks = (gmax + 4) >> 2;      // 64-wide chunks softmax reads
  const int gpad = nchunks * 4 - 1;         // granules written (incl. fill)
  const int ntv = ((gmax - wv) >> 3) + 1;   // compute granules this wave (>=4)

  // pad-mask element-width detect (bool bytes vs int32/f32 words); r5-proven.
  bool is_byte = false;
#pragma unroll
  for (int j = 1; j < 256; ++j)
    if ((j & 3) && padraw[j] == 1) is_byte = true;
  const int* ipad = (const int*)padraw;

  // per-lane pad bits; granule for slot nt is g = nt*8 + wv
  unsigned pmask = 0;
#pragma unroll
  for (int nt = 0; nt < 8; ++nt) {
    int kpos = (nt * 8 + wv) * 16 + lo;
    int pk = is_byte ? (int)padraw[b * 1024 + kpos]
                     : (ipad[b * 1024 + kpos] != 0 ? 1 : 0);
    pmask |= (unsigned)(pk != 0) << nt;
  }

  float macc[2][16];
#pragma unroll
  for (int rr = 0; rr < 2; ++rr)
#pragma unroll
    for (int i = 0; i < 16; ++i) macc[rr][i] = 0.f;

  // Q prefetch for h = 0 (loop-carried across heads)
  const __hip_bfloat16* qbase =
      qh + ((size_t)(b * 16) * 512 + (size_t)qt * 16) * 64;
  bf16x8 qf0 = *(const bf16x8*)(qbase + (size_t)lo * 64 + hi * 8);
  bf16x8 qf1 = *(const bf16x8*)(qbase + (size_t)lo * 64 + 32 + hi * 8);

  for (int h = 0; h < 16; ++h) {
    const __hip_bfloat16* kbh = kh + (size_t)(b * 16 + h) * 1024 * 64;
    const __hip_bfloat16* vbh = vt + (size_t)(b * 16 + h) * 64 * 1024;

    // ---- fill granules (gmax, gpad] with -1e30 (<=3 per block, no MFMA) ----
    for (int g = gmax + 1; g <= gpad; ++g) {
      if ((g & 7) == wv) {
        int kpos = g * 16 + lo;
#pragma unroll
        for (int r = 0; r < 4; ++r) {
          int q = hi * 4 + r;
          Sld[q * 1024 + (kpos ^ swz(q))] = -1e30f;
        }
      }
    }

    // ---- S = Q K^T / 8 + mask; interleaved granules, 2-deep K ring ----
    bf16x8 kbuf[2][2];
#pragma unroll
    for (int p = 0; p < 2; ++p) {
      int kr = (p * 8 + wv) * 16 + lo;        // ntv >= 4, both always valid
      kbuf[p][0] = *(const bf16x8*)(kbh + (size_t)kr * 64 + hi * 8);
      kbuf[p][1] = *(const bf16x8*)(kbh + (size_t)kr * 64 + 32 + hi * 8);
    }
#pragma unroll
    for (int nt = 0; nt < 8; ++nt) {
      if (nt >= ntv) break;                   // wave-uniform skip
      bf16x8 ck0 = kbuf[nt & 1][0], ck1 = kbuf[nt & 1][1];
      if (nt + 2 < ntv) {
        int kr = ((nt + 2) * 8 + wv) * 16 + lo;
        kbuf[nt & 1][0] = *(const bf16x8*)(kbh + (size_t)kr * 64 + hi * 8);
        kbuf[nt & 1][1] = *(const bf16x8*)(kbh + (size_t)kr * 64 + 32 + hi * 8);
      }
      f32x4 sa = vz;
      sa = __builtin_amdgcn_mfma_f32_16x16x32_bf16(qf0, ck0, sa, 0, 0, 0);
      sa = __builtin_amdgcn_mfma_f32_16x16x32_bf16(qf1, ck1, sa, 0, 0, 0);
      int kpos = (nt * 8 + wv) * 16 + lo;
      int pk = (pmask >> nt) & 1;
#pragma unroll
      for (int r = 0; r < 4; ++r) {
        int q = hi * 4 + r;
        int qg = 512 + qt * 16 + q;
        float sv = sa[r] * 0.125f;
        bool msk = (kpos > qg) || (kpos < qg && pk != 0);
        Sld[q * 1024 + (kpos ^ swz(q))] = msk ? -1e30f : sv;
      }
    }
    __syncthreads();   // sync1: S complete over [0, gpad]

    // ---- softmax (wave owns rows [wv*2,+2)); bounded to nchunks ----
#pragma unroll
    for (int rr = 0; rr < 2; ++rr) {
      int q = wv * 2 + rr;
      const int c = swz(q);
      float* row = Sld + q * 1024;
      float v[16], mx = -1e30f;
#pragma unroll
      for (int i = 0; i < 16; ++i) {
        if (i >= nchunks) break;
        v[i] = row[(lane + i * 64) ^ c];
        mx = fmaxf(mx, v[i]);
      }
#pragma unroll
      for (int off = 32; off > 0; off >>= 1) mx = fmaxf(mx, __shfl_xor(mx, off));
      float sum = 0.f;
#pragma unroll
      for (int i = 0; i < 16; ++i) {
        if (i >= nchunks) break;
        v[i] = __expf(v[i] - mx);
        sum += v[i];
      }
#pragma unroll
      for (int off = 32; off > 0; off >>= 1) sum += __shfl_xor(sum, off);
      float invs = 1.0f / sum;
      short* prow = Pld + q * 2048 + 1024;   // f32 row q words [512,1024)
#pragma unroll
      for (int i = 0; i < 16; ++i) {
        if (i >= nchunks) break;
        float p = v[i] * invs;
        prow[(lane + i * 64) ^ c] = f2bs(p);
        macc[rr][i] += p;
      }
    }
    __syncthreads();   // sync2: P complete

    // ---- O = P V ; wg owns d cols [wg*16,+16); halves interleave slices ----
    // half does kc = 2j+half for j < nchunks (P beyond nchunks*64 undefined,
    // never read; zero-P slices inside are exact +0 contributions).
    f32x4 oacc = vz;
    {
      const short* prow = Pld + lo * 2048 + 1024;
      const int cl = swz(lo);
      const __hip_bfloat16* vrow = vbh + (size_t)(wg * 16 + lo) * 1024;
      bf16x8 vbuf[2];
#pragma unroll
      for (int p = 0; p < 2; ++p) {           // nchunks >= 9, both valid
        int kc = 2 * p + half;
        vbuf[p] = *(const bf16x8*)(vrow + kc * 32 + hi * 8);
      }
#pragma unroll
      for (int j = 0; j < 16; ++j) {
        if (j >= nchunks) break;
        int kc = 2 * j + half;
        bf16x8 cv = vbuf[j & 1];
        if (j + 2 < nchunks) {
          int kcn = 2 * (j + 2) + half;
          vbuf[j & 1] = *(const bf16x8*)(vrow + kcn * 32 + hi * 8);
        }
        bf16x8 pa = *(const bf16x8*)&prow[(kc * 32 + hi * 8) ^ cl];
        oacc = __builtin_amdgcn_mfma_f32_16x16x32_bf16(pa, cv, oacc, 0, 0, 0);
      }
    }

    // Q prefetch for next head (hides under osc/oat stores + next QK setup)
    if (h < 15) {
      const __hip_bfloat16* qn = qbase + (size_t)(h + 1) * 512 * 64;
      qf0 = *(const bf16x8*)(qn + (size_t)lo * 64 + hi * 8);
      qf1 = *(const bf16x8*)(qn + (size_t)lo * 64 + 32 + hi * 8);
    }

    if (half == 1) {
#pragma unroll
      for (int r = 0; r < 4; ++r) osc[(wg * 64 + lane) * 4 + r] = oacc[r];
    }
    __syncthreads();   // sync3: all P-reads done + osc visible
    if (half == 0) {
#pragma unroll
      for (int r = 0; r < 4; ++r) {
        float o = oacc[r] + osc[(wg * 64 + lane) * 4 + r];
        int q = qt * 16 + hi * 4 + r;
        oat[((size_t)b * 512 + q) * 1024 + h * 64 + wg * 16 + lo] =
            __float2bfloat16(o);
      }
    }
    // sync4 not needed: half1's next osc-write is ordered after next-head
    // sync2 > half0's osc-read here; S vs osc are disjoint LDS regions.
  }

  // ---- head-mean store (full coverage; skipped chunks are exact zeros) ----
#pragma unroll
  for (int rr = 0; rr < 2; ++rr) {
    size_t mrow = ((size_t)b * 512 + (size_t)qt * 16 + wv * 2 + rr) * 1024;
#pragma unroll
    for (int i = 0; i < 16; ++i)
      mean_out[mrow + lane + i * 64] = macc[rr][i] * 0.0625f;
  }
}

// ---------------- gate elementwise kernels (RbZb stride 2048) --------------
__global__ __launch_bounds__(256) void k_rx(const float* __restrict__ RbZb,
                                            const float* __restrict__ x,
                                            short* __restrict__ rx) {
  size_t base = ((size_t)blockIdx.x * 256 + threadIdx.x) * 4;
  int row = (int)(base >> 10), col = (int)(base & 1023);
  int b = row >> 9, s = row & 511;
  const float* xp = x + ((size_t)(b * 1024 + 512 + s) << 10) + col;
  f32x4 rv = *(const f32x4*)(RbZb + (size_t)row * 2048 + col);
  f32x4 xv = *(const f32x4*)xp;
  typedef __attribute__((ext_vector_type(4))) short s16x4;
  s16x4 o;
#pragma unroll
  for (int j = 0; j < 4; ++j) {
    float r = 1.f / (1.f + __expf(-rv[j]));
    o[j] = f2bs(r * xv[j]);
  }
  *(s16x4*)(rx + base) = o;
}

__global__ __launch_bounds__(256) void k_final(const float* __restrict__ RbZb,
                                               const float* __restrict__ Hb,
                                               const float* __restrict__ x,
                                               float* __restrict__ out0) {
  size_t base = ((size_t)blockIdx.x * 256 + threadIdx.x) * 4;
  int row = (int)(base >> 10), col = (int)(base & 1023);
  int b = row >> 9, s = row & 511;
  const float* xp = x + ((size_t)(b * 1024 + 512 + s) << 10) + col;
  f32x4 zv = *(const f32x4*)(RbZb + (size_t)row * 2048 + 1024 + col);
  f32x4 hv = *(const f32x4*)(Hb + base);
  f32x4 xv = *(const f32x4*)xp;
  f32x4 o;
#pragma unroll
  for (int j = 0; j < 4; ++j) {
    float z = 1.f / (1.f + __expf(-zv[j]));
    float hh = tanhf(hv[j]);
    o[j] = (1.f - z) * xv[j] + z * hh;
  }
  *(f32x4*)(out0 + base) = o;
}

// ============================================================================
extern "C" void kernel_launch(void* const* d_in, const int* in_sizes, int n_in,
                              void* d_out, int out_size, void* d_ws, size_t ws_size,
                              hipStream_t stream) {
  const float* key_in = (const float*)d_in[0];
  const int* key_index = (const int*)d_in[1];
  const unsigned char* pad = (const unsigned char*)d_in[2];
  const float* bq  = (const float*)d_in[4];
  const float* bk  = (const float*)d_in[6];
  const float* bv  = (const float*)d_in[8];
  const float* bo  = (const float*)d_in[10];
  const float* bxr = (const float*)d_in[12];
  const float* byr = (const float*)d_in[14];
  const float* bxz = (const float*)d_in[16];
  const float* byz = (const float*)d_in[18];
  const float* bxg = (const float*)d_in[20];
  const float* byg = (const float*)d_in[22];

  char* ws = (char*)d_ws;
  short* wt = (short*)(ws + OFF_WT);
  float* tab = (float*)(ws + OFF_TAB);
  short* xbf = (short*)(ws + OFF_XBF);
  __hip_bfloat16* qh = (__hip_bfloat16*)(ws + OFF_QH);
  __hip_bfloat16* kh = (__hip_bfloat16*)(ws + OFF_KH);
  __hip_bfloat16* vt = (__hip_bfloat16*)(ws + OFF_VT);
  double* inv = (double*)(ws + OFF_INV);
  float* RbZb = (float*)(ws + OFF_RBZB);
  __hip_bfloat16* oat = (__hip_bfloat16*)(ws + OFF_OAT);
  short* o2 = (short*)(ws + OFF_O2);
  short* rx = (short*)(ws + OFF_RX);
  float* Hb = (float*)(ws + OFF_HB);

  float* out0 = (float*)d_out;
  float* out1 = out0 + (size_t)8388608;

  // wt slot order: 0=q 1=k 2=v 3=o 4=xr 5=xz 6=yr 7=yz 8=xg 9=yg
  W10 wargs;
  wargs.p[0] = (const float*)d_in[3];   // Wq
  wargs.p[1] = (const float*)d_in[5];   // Wk
  wargs.p[2] = (const float*)d_in[7];   // Wv
  wargs.p[3] = (const float*)d_in[9];   // Wo
  wargs.p[4] = (const float*)d_in[11];  // Wxr
  wargs.p[5] = (const float*)d_in[15];  // Wxz
  wargs.p[6] = (const float*)d_in[13];  // Wyr
  wargs.p[7] = (const float*)d_in[17];  // Wyz
  wargs.p[8] = (const float*)d_in[19];  // Wxg
  wargs.p[9] = (const float*)d_in[21];  // Wyg

  k_cvtx<<<8192, 256, 0, stream>>>(key_in, xbf);
  k_wt<<<dim3(32, 32, 10), 256, 0, stream>>>(wargs, wt);
  k_tabinv<<<1, 512, 0, stream>>>(inv);
  k_table<<<10000, 256, 0, stream>>>(tab, inv);

  // q/k projections with fused RoPE; v with fused transpose
  k_gemm<1, CM_ROPE><<<dim3(64, 8), 256, 0, stream>>>(
      xbf, wt + (size_t)0 * 1048576, bq, nullptr, (void*)qh, 0, tab, key_index, 9, 512);
  k_gemm<0, CM_ROPE><<<dim3(128, 8), 256, 0, stream>>>(
      xbf, wt + (size_t)1 * 1048576, bk, nullptr, (void*)kh, 0, tab, key_index, 10, 0);
  k_gemm<0, CM_VT><<<dim3(128, 8), 256, 0, stream>>>(
      xbf, wt + (size_t)2 * 1048576, bv, nullptr, (void*)vt, 0, nullptr, nullptr, 0, 0);

  // attention (1D grid, b-major XCD swizzle; mean written directly)
  k_attn<<<dim3(512), 512, 0, stream>>>(qh, kh, vt, pad, out1, oat);

  // output projection + merged gates
  k_gemm<0, CM_BF16><<<dim3(64, 8), 256, 0, stream>>>(
      (const short*)oat, wt + (size_t)3 * 1048576, bo, nullptr, (void*)o2, 1024,
      nullptr, nullptr, 0, 0);
  k_gemm<1, CM_F32><<<dim3(64, 16), 256, 0, stream>>>(
      xbf, wt + (size_t)4 * 1048576, bxr, bxz, (void*)RbZb, 2048,
      nullptr, nullptr, 0, 0);
  k_gemm<0, CM_F32ACC><<<dim3(64, 16), 256, 0, stream>>>(
      o2, wt + (size_t)6 * 1048576, byr, byz, (void*)RbZb, 2048,
      nullptr, nullptr, 0, 0);
  k_rx<<<8192, 256, 0, stream>>>(RbZb, key_in, rx);
  k_gemm<0, CM_F32><<<dim3(64, 8), 256, 0, stream>>>(
      rx, wt + (size_t)8 * 1048576, bxg, nullptr, (void*)Hb, 1024,
      nullptr, nullptr, 0, 0);
  k_gemm<0, CM_F32ACC><<<dim3(64, 8), 256, 0, stream>>>(
      o2, wt + (size_t)9 * 1048576, byg, nullptr, (void*)Hb, 1024,
      nullptr, nullptr, 0, 0);
  k_final<<<8192, 256, 0, stream>>>(RbZb, Hb, key_in, out0);
}

// Round 17
// 766.835 us; speedup vs baseline: 3.0159x; 3.0159x over previous
//
#include <hip/hip_runtime.h>
#include <hip/hip_bf16.h>

// ============================================================================
// EpisodeMultiheadAttentionBlock — round 17 = byte-exact r15 (measured best:
// 768.4 µs). r16's causal-skip regressed 3x: `break` inside #pragma unroll
// defeated unrolling -> runtime-indexed kbuf/vbuf/v arrays -> scratch +
// per-iter branching (rule #20). Five attn restructurings (r11-r14, r16) all
// lost to this structure; reverting and holding.
//  * k_attn: r10 v5 (512 thr, (512,2), 69632B LDS, 2-deep rings, 3 barriers,
//    VGPR 116 no-spill, b-major XCD swizzle, reg head-mean).
//  * GEMM side: templated epilogues (ROPE/VT fused), merged N=2048 gates.
// ============================================================================

typedef __attribute__((ext_vector_type(8))) short bf16x8;
typedef __attribute__((ext_vector_type(4))) float f32x4;

__device__ __forceinline__ short f2bs(float f) {
  union { __hip_bfloat16 h; short s; } u; u.h = __float2bfloat16(f); return u.s;
}

// ---------------- workspace layout (bytes); peak 192,446,464 ---------------
static constexpr size_t OFF_WT   = 0;            // 10 x 1M bf16 W^T (20,971,520)
static constexpr size_t OFF_TAB  = 20971520;     // f32 (cos,sin) 5000x512x2 (20,480,000)
static constexpr size_t OFF_XBF  = 41451520;     // bf16 x [16384][1024] (33,554,432)
static constexpr size_t OFF_QH   = 75005952;     // qh bf16 [b,h][512][64] (16,777,216)
static constexpr size_t OFF_KH   = 91783168;     // kh bf16 [b,h][1024][64] (33,554,432)
static constexpr size_t OFF_VT   = 125337600;    // vT bf16 [b,h][64][1024] (33,554,432)
static constexpr size_t OFF_OAT  = 158892032;    // attn-out bf16 (16,777,216)
static constexpr size_t OFF_O2   = 175669248;    // o2 bf16 (16,777,216) -> 192,446,464
// overlays (lifetimes audited against launch order):
static constexpr size_t OFF_INV  = OFF_OAT;      // f64 inv[512] (4KB); dead before oat
static constexpr size_t OFF_RBZB = 75005952;     // f32 [8192][2048] (67,108,864) post-attn
static constexpr size_t OFF_RX   = 142114816;    // rx bf16 (16,777,216) over dead vt-tail
static constexpr size_t OFF_HB   = OFF_XBF;      // Hb f32 (33,554,432) over dead xbf

// swizzle for the 16x1024 S/P tile: spreads 64 lanes over all 32 banks.
__device__ __forceinline__ int swz(int q) { return ((q & 3) << 3) ^ ((q & 12) << 2); }

// ---------------- x: f32 -> bf16 ------------------------------------------
__global__ __launch_bounds__(256) void k_cvtx(const float* __restrict__ x,
                                              short* __restrict__ xbf) {
  size_t i = ((size_t)blockIdx.x * 256 + threadIdx.x) * 8;
  f32x4 a = *(const f32x4*)(x + i);
  f32x4 b = *(const f32x4*)(x + i + 4);
  bf16x8 o;
  o[0] = f2bs(a[0]); o[1] = f2bs(a[1]); o[2] = f2bs(a[2]); o[3] = f2bs(a[3]);
  o[4] = f2bs(b[0]); o[5] = f2bs(b[1]); o[6] = f2bs(b[2]); o[7] = f2bs(b[3]);
  *(bf16x8*)(xbf + i) = o;
}

// ---------------- rope table: inv hoisted (f64), then sincos ---------------
__global__ void k_tabinv(double* __restrict__ inv) {
  int i = threadIdx.x;  // 512 threads, 1 block
  inv[i] = pow(10000.0, -(double)i / 512.0);
}
__global__ __launch_bounds__(256) void k_table(float* __restrict__ tab,
                                               const double* __restrict__ inv) {
  int i = blockIdx.x * 256 + threadIdx.x;
  if (i >= 5000 * 512) return;
  int pos = i >> 9, fi = i & 511;
  double ds, dc;
  sincos((double)pos * inv[fi], &ds, &dc);
  tab[2 * i] = (float)dc;
  tab[2 * i + 1] = (float)ds;
}

// ---------------- weight transpose: W[k][n] f32 -> Wt[n][k] bf16 -----------
struct W10 { const float* p[10]; };
__global__ __launch_bounds__(256) void k_wt(W10 wsrc, short* __restrict__ wt) {
  __shared__ short t[32][33];
  int kb = blockIdx.x * 32, nb = blockIdx.y * 32, wi = blockIdx.z;
  const float* src = wsrc.p[wi];
  int tid = threadIdx.x;
#pragma unroll
  for (int e = 0; e < 4; ++e) {
    int idx = e * 256 + tid;
    int kr = idx >> 5, nc = idx & 31;
    t[nc][kr] = f2bs(src[(size_t)(kb + kr) * 1024 + nb + nc]);
  }
  __syncthreads();
  short* dst = wt + (size_t)wi * 1024 * 1024;
#pragma unroll
  for (int e = 0; e < 4; ++e) {
    int idx = e * 256 + tid;
    int nr = idx >> 5, kc = idx & 31;
    dst[(size_t)(nb + nr) * 1024 + kb + kc] = t[nr][kc];
  }
}

// ---------------- generic 128x128 MFMA GEMM, templated epilogue ------------
enum { CM_BF16 = 0, CM_F32 = 2, CM_F32ACC = 3, CM_VT = 4, CM_ROPE = 5 };

template <int AMODE, int CMODE>
__global__ __launch_bounds__(256) void k_gemm(
    const short* __restrict__ A, const short* __restrict__ Bt,
    const float* __restrict__ bias, const float* __restrict__ bias2,
    void* __restrict__ Cout, int ldc,
    const float* __restrict__ tab, const int* __restrict__ kidx,
    int sshift, int qoff) {
  __shared__ __align__(16) short lA[128 * 32];
  __shared__ __align__(16) short lB[128 * 32];
  const int tid = threadIdx.x;
  const int lane = tid & 63;
  const int wv = tid >> 6;
  const int wm = wv >> 1, wn = wv & 1;
  const int lo = lane & 15, hi = lane >> 4;
  const int tm0 = blockIdx.x * 128;
  const int tn0 = blockIdx.y * 128;

  const f32x4 vz = {0.f, 0.f, 0.f, 0.f};
  f32x4 acc[4][4];
#pragma unroll
  for (int m = 0; m < 4; ++m)
#pragma unroll
    for (int n = 0; n < 4; ++n) acc[m][n] = vz;

  for (int kt = 0; kt < 32; ++kt) {
    const int k0 = kt * 32;
    __syncthreads();
#pragma unroll
    for (int i = 0; i < 2; ++i) {
      int f = i * 256 + tid;
      int r = f >> 2;
      int cb = (f & 3) * 16;
      int arow = tm0 + r;
      if (AMODE) arow = ((arow >> 9) << 10) + 512 + (arow & 511);
      const char* ga = (const char*)(A + (size_t)arow * 1024 + k0) + cb;
      __builtin_amdgcn_global_load_lds(
          (const __attribute__((address_space(1))) void*)ga,
          (__attribute__((address_space(3))) void*)((char*)lA + (size_t)(i * 256 + wv * 64) * 16),
          16, 0, 0);
      int brow = tn0 + r;
      const char* gb = (const char*)(Bt + (size_t)brow * 1024 + k0) + cb;
      __builtin_amdgcn_global_load_lds(
          (const __attribute__((address_space(1))) void*)gb,
          (__attribute__((address_space(3))) void*)((char*)lB + (size_t)(i * 256 + wv * 64) * 16),
          16, 0, 0);
    }
    __syncthreads();
    bf16x8 af[4], bfr[4];
#pragma unroll
    for (int m = 0; m < 4; ++m)
      af[m] = *(const bf16x8*)&lA[(wm * 64 + m * 16 + lo) * 32 + hi * 8];
#pragma unroll
    for (int n = 0; n < 4; ++n)
      bfr[n] = *(const bf16x8*)&lB[(wn * 64 + n * 16 + lo) * 32 + hi * 8];
#pragma unroll
    for (int m = 0; m < 4; ++m)
#pragma unroll
      for (int n = 0; n < 4; ++n)
        acc[m][n] = __builtin_amdgcn_mfma_f32_16x16x32_bf16(af[m], bfr[n], acc[m][n], 0, 0, 0);
  }

  if constexpr (CMODE == CM_ROPE) {
    __hip_bfloat16* out = (__hip_bfloat16*)Cout;
    const float2* t2 = (const float2*)tab;
    const int srows = 1 << sshift;
    const float sgn = (lane & 1) ? 1.f : -1.f;
#pragma unroll
    for (int m = 0; m < 4; ++m) {
      int row_base = tm0 + wm * 64 + m * 16 + hi * 4;
#pragma unroll
      for (int n = 0; n < 4; ++n) {
        int col = tn0 + wn * 64 + n * 16 + lo;
        float bsv = bias[col];
        int j = col >> 1, hh = col >> 6, dd = col & 63;
#pragma unroll
        for (int r = 0; r < 4; ++r) {
          int row = row_base + r;
          int bb = row >> sshift, ss = row & (srows - 1);
          int idx = kidx[bb * 1024 + qoff + ss];
          float2 cs = t2[(size_t)idx * 512 + j];
          float val = acc[m][n][r] + bsv;
          float part = __shfl_xor(val, 1);
          float rot = val * cs.x + sgn * part * cs.y;
          out[((size_t)(bb * 16 + hh) * srows + ss) * 64 + dd] = __float2bfloat16(rot);
        }
      }
    }
  } else if constexpr (CMODE == CM_VT) {
    __hip_bfloat16* out = (__hip_bfloat16*)Cout;
#pragma unroll
    for (int m = 0; m < 4; ++m) {
      int row_base = tm0 + wm * 64 + m * 16 + hi * 4;
#pragma unroll
      for (int n = 0; n < 4; ++n) {
        int col = tn0 + wn * 64 + n * 16 + lo;
        float bsv = bias[col];
        int hh = col >> 6, dd = col & 63;
#pragma unroll
        for (int r = 0; r < 4; ++r) {
          int row = row_base + r;
          int bb = row >> 10, ss = row & 1023;
          out[((size_t)(bb * 16 + hh) * 64 + dd) * 1024 + ss] =
              __float2bfloat16(acc[m][n][r] + bsv);
        }
      }
    }
  } else if constexpr (CMODE == CM_F32 || CMODE == CM_F32ACC) {
    float* out = (float*)Cout;
#pragma unroll
    for (int m = 0; m < 4; ++m) {
      int row_base = tm0 + wm * 64 + m * 16 + hi * 4;
#pragma unroll
      for (int n = 0; n < 4; ++n) {
        int col = tn0 + wn * 64 + n * 16 + lo;
        float bsv = (col < 1024 || !bias2) ? bias[col] : bias2[col - 1024];
#pragma unroll
        for (int r = 0; r < 4; ++r) {
          size_t off = (size_t)(row_base + r) * ldc + col;
          float val = acc[m][n][r] + bsv;
          if constexpr (CMODE == CM_F32ACC) val += out[off];
          out[off] = val;
        }
      }
    }
  } else {
    __hip_bfloat16* out = (__hip_bfloat16*)Cout;
#pragma unroll
    for (int m = 0; m < 4; ++m) {
      int row_base = tm0 + wm * 64 + m * 16 + hi * 4;
#pragma unroll
      for (int n = 0; n < 4; ++n) {
        int col = tn0 + wn * 64 + n * 16 + lo;
        float bsv = bias[col];
#pragma unroll
        for (int r = 0; r < 4; ++r) {
          size_t off = (size_t)(row_base + r) * ldc + col;
          out[off] = __float2bfloat16(acc[m][n][r] + bsv);
        }
      }
    }
  }
}

// ---------------- attention (r10 v5 structure) -----------------------------
// 1D grid 512 (wgid = qt*16 + b => XCD = b%8). 512 thr / 8 waves.
// launch_bounds (512,2). 2-deep K/V rings. 3 barriers/head. osc separate LDS.
__global__ __launch_bounds__(512, 2) void k_attn(
    const __hip_bfloat16* __restrict__ qh,
    const __hip_bfloat16* __restrict__ kh,
    const __hip_bfloat16* __restrict__ vt,
    const unsigned char* __restrict__ padraw,
    float* __restrict__ mean_out,
    __hip_bfloat16* __restrict__ oat) {
  __shared__ float Sld[16 * 1024];     // 64 KiB; bf16 P overlays row second halves
  __shared__ float osc[4 * 64 * 4];    // 4 KiB PV combine scratch
  short* Pld = (short*)Sld;
  const int wgid = blockIdx.x;
  const int b = wgid & 15, qt = wgid >> 4;
  const int tid = threadIdx.x, lane = tid & 63, wv = tid >> 6;
  const int lo = lane & 15, hi = lane >> 4;
  const int wg = wv & 3, half = wv >> 2;
  const f32x4 vz = {0.f, 0.f, 0.f, 0.f};

  // pad-mask element-width detect (bool bytes vs int32/f32 words); r5-proven.
  bool is_byte = false;
#pragma unroll
  for (int j = 1; j < 256; ++j)
    if ((j & 3) && padraw[j] == 1) is_byte = true;
  const int* ipad = (const int*)padraw;

  // per-lane pad bits for this wave's 8 kpos slots (kpos = wv*128+nt*16+lo)
  unsigned pmask = 0;
#pragma unroll
  for (int nt = 0; nt < 8; ++nt) {
    int kpos = wv * 128 + nt * 16 + lo;
    int pk = is_byte ? (int)padraw[b * 1024 + kpos]
                     : (ipad[b * 1024 + kpos] != 0 ? 1 : 0);
    pmask |= (unsigned)(pk != 0) << nt;
  }

  float macc[2][16];
#pragma unroll
  for (int rr = 0; rr < 2; ++rr)
#pragma unroll
    for (int i = 0; i < 16; ++i) macc[rr][i] = 0.f;

  // Q prefetch for h = 0 (loop-carried across heads)
  const __hip_bfloat16* qbase =
      qh + ((size_t)(b * 16) * 512 + (size_t)qt * 16) * 64;
  bf16x8 qf0 = *(const bf16x8*)(qbase + (size_t)lo * 64 + hi * 8);
  bf16x8 qf1 = *(const bf16x8*)(qbase + (size_t)lo * 64 + 32 + hi * 8);

  for (int h = 0; h < 16; ++h) {
    const __hip_bfloat16* kbh = kh + (size_t)(b * 16 + h) * 1024 * 64;
    const __hip_bfloat16* vbh = vt + (size_t)(b * 16 + h) * 64 * 1024;

    // ---- S = Q K^T / 8 + mask; 2-deep K prefetch ring ----
    bf16x8 kbuf[2][2];
#pragma unroll
    for (int p = 0; p < 2; ++p) {
      int kr = wv * 128 + p * 16 + lo;
      kbuf[p][0] = *(const bf16x8*)(kbh + (size_t)kr * 64 + hi * 8);
      kbuf[p][1] = *(const bf16x8*)(kbh + (size_t)kr * 64 + 32 + hi * 8);
    }
#pragma unroll
    for (int nt = 0; nt < 8; ++nt) {
      bf16x8 ck0 = kbuf[nt & 1][0], ck1 = kbuf[nt & 1][1];
      if (nt < 6) {
        int kr = wv * 128 + (nt + 2) * 16 + lo;
        kbuf[nt & 1][0] = *(const bf16x8*)(kbh + (size_t)kr * 64 + hi * 8);
        kbuf[nt & 1][1] = *(const bf16x8*)(kbh + (size_t)kr * 64 + 32 + hi * 8);
      }
      f32x4 sa = vz;
      sa = __builtin_amdgcn_mfma_f32_16x16x32_bf16(qf0, ck0, sa, 0, 0, 0);
      sa = __builtin_amdgcn_mfma_f32_16x16x32_bf16(qf1, ck1, sa, 0, 0, 0);
      int kpos = wv * 128 + nt * 16 + lo;
      int pk = (pmask >> nt) & 1;
#pragma unroll
      for (int r = 0; r < 4; ++r) {
        int q = hi * 4 + r;
        int qg = 512 + qt * 16 + q;
        float sv = sa[r] * 0.125f;
        bool msk = (kpos > qg) || (kpos < qg && pk != 0);
        Sld[q * 1024 + (kpos ^ swz(q))] = msk ? -1e30f : sv;
      }
    }
    __syncthreads();   // sync1: S complete

    // ---- softmax (wave owns rows [wv*2,+2)); P -> bf16 row second half ----
#pragma unroll
    for (int rr = 0; rr < 2; ++rr) {
      int q = wv * 2 + rr;
      const int c = swz(q);
      float* row = Sld + q * 1024;
      float v[16], mx = -1e30f;
#pragma unroll
      for (int i = 0; i < 16; ++i) {
        v[i] = row[(lane + i * 64) ^ c];
        mx = fmaxf(mx, v[i]);
      }
#pragma unroll
      for (int off = 32; off > 0; off >>= 1) mx = fmaxf(mx, __shfl_xor(mx, off));
      float sum = 0.f;
#pragma unroll
      for (int i = 0; i < 16; ++i) { v[i] = __expf(v[i] - mx); sum += v[i]; }
#pragma unroll
      for (int off = 32; off > 0; off >>= 1) sum += __shfl_xor(sum, off);
      float invs = 1.0f / sum;
      short* prow = Pld + q * 2048 + 1024;   // f32 row q words [512,1024)
#pragma unroll
      for (int i = 0; i < 16; ++i) {
        float p = v[i] * invs;
        prow[(lane + i * 64) ^ c] = f2bs(p);
        macc[rr][i] += p;
      }
    }
    __syncthreads();   // sync2: P complete

    // ---- O = P V ; wg owns d cols [wg*16,+16), half owns kc range ----
    // 2-deep V prefetch ring.
    f32x4 oacc = vz;
    {
      const short* prow = Pld + lo * 2048 + 1024;
      const int cl = swz(lo);
      const int kcg = half * 16;
      const __hip_bfloat16* vrow = vbh + (size_t)(wg * 16 + lo) * 1024;
      bf16x8 vbuf[2];
#pragma unroll
      for (int p = 0; p < 2; ++p)
        vbuf[p] = *(const bf16x8*)(vrow + (kcg + p) * 32 + hi * 8);
#pragma unroll
      for (int kc = 0; kc < 16; ++kc) {
        bf16x8 cv = vbuf[kc & 1];
        if (kc < 14)
          vbuf[kc & 1] = *(const bf16x8*)(vrow + (kcg + kc + 2) * 32 + hi * 8);
        bf16x8 pa = *(const bf16x8*)&prow[((kcg + kc) * 32 + hi * 8) ^ cl];
        oacc = __builtin_amdgcn_mfma_f32_16x16x32_bf16(pa, cv, oacc, 0, 0, 0);
      }
    }

    // Q prefetch for next head (hides under osc/oat stores + next QK setup)
    if (h < 15) {
      const __hip_bfloat16* qn = qbase + (size_t)(h + 1) * 512 * 64;
      qf0 = *(const bf16x8*)(qn + (size_t)lo * 64 + hi * 8);
      qf1 = *(const bf16x8*)(qn + (size_t)lo * 64 + 32 + hi * 8);
    }

    if (half == 1) {
#pragma unroll
      for (int r = 0; r < 4; ++r) osc[(wg * 64 + lane) * 4 + r] = oacc[r];
    }
    __syncthreads();   // sync3: all P-reads done + osc visible
    if (half == 0) {
#pragma unroll
      for (int r = 0; r < 4; ++r) {
        float o = oacc[r] + osc[(wg * 64 + lane) * 4 + r];
        int q = qt * 16 + hi * 4 + r;
        oat[((size_t)b * 512 + q) * 1024 + h * 64 + wg * 16 + lo] =
            __float2bfloat16(o);
      }
    }
    // sync4 not needed: half1's next osc-write is ordered after next-head
    // sync2 > half0's osc-read here; S vs osc are disjoint LDS regions.
  }

  // ---- head-mean store (full coverage of out1; no atomics) ----
#pragma unroll
  for (int rr = 0; rr < 2; ++rr) {
    size_t mrow = ((size_t)b * 512 + (size_t)qt * 16 + wv * 2 + rr) * 1024;
#pragma unroll
    for (int i = 0; i < 16; ++i)
      mean_out[mrow + lane + i * 64] = macc[rr][i] * 0.0625f;
  }
}

// ---------------- gate elementwise kernels (RbZb stride 2048) --------------
__global__ __launch_bounds__(256) void k_rx(const float* __restrict__ RbZb,
                                            const float* __restrict__ x,
                                            short* __restrict__ rx) {
  size_t base = ((size_t)blockIdx.x * 256 + threadIdx.x) * 4;
  int row = (int)(base >> 10), col = (int)(base & 1023);
  int b = row >> 9, s = row & 511;
  const float* xp = x + ((size_t)(b * 1024 + 512 + s) << 10) + col;
  f32x4 rv = *(const f32x4*)(RbZb + (size_t)row * 2048 + col);
  f32x4 xv = *(const f32x4*)xp;
  typedef __attribute__((ext_vector_type(4))) short s16x4;
  s16x4 o;
#pragma unroll
  for (int j = 0; j < 4; ++j) {
    float r = 1.f / (1.f + __expf(-rv[j]));
    o[j] = f2bs(r * xv[j]);
  }
  *(s16x4*)(rx + base) = o;
}

__global__ __launch_bounds__(256) void k_final(const float* __restrict__ RbZb,
                                               const float* __restrict__ Hb,
                                               const float* __restrict__ x,
                                               float* __restrict__ out0) {
  size_t base = ((size_t)blockIdx.x * 256 + threadIdx.x) * 4;
  int row = (int)(base >> 10), col = (int)(base & 1023);
  int b = row >> 9, s = row & 511;
  const float* xp = x + ((size_t)(b * 1024 + 512 + s) << 10) + col;
  f32x4 zv = *(const f32x4*)(RbZb + (size_t)row * 2048 + 1024 + col);
  f32x4 hv = *(const f32x4*)(Hb + base);
  f32x4 xv = *(const f32x4*)xp;
  f32x4 o;
#pragma unroll
  for (int j = 0; j < 4; ++j) {
    float z = 1.f / (1.f + __expf(-zv[j]));
    float hh = tanhf(hv[j]);
    o[j] = (1.f - z) * xv[j] + z * hh;
  }
  *(f32x4*)(out0 + base) = o;
}

// ============================================================================
extern "C" void kernel_launch(void* const* d_in, const int* in_sizes, int n_in,
                              void* d_out, int out_size, void* d_ws, size_t ws_size,
                              hipStream_t stream) {
  const float* key_in = (const float*)d_in[0];
  const int* key_index = (const int*)d_in[1];
  const unsigned char* pad = (const unsigned char*)d_in[2];
  const float* bq  = (const float*)d_in[4];
  const float* bk  = (const float*)d_in[6];
  const float* bv  = (const float*)d_in[8];
  const float* bo  = (const float*)d_in[10];
  const float* bxr = (const float*)d_in[12];
  const float* byr = (const float*)d_in[14];
  const float* bxz = (const float*)d_in[16];
  const float* byz = (const float*)d_in[18];
  const float* bxg = (const float*)d_in[20];
  const float* byg = (const float*)d_in[22];

  char* ws = (char*)d_ws;
  short* wt = (short*)(ws + OFF_WT);
  float* tab = (float*)(ws + OFF_TAB);
  short* xbf = (short*)(ws + OFF_XBF);
  __hip_bfloat16* qh = (__hip_bfloat16*)(ws + OFF_QH);
  __hip_bfloat16* kh = (__hip_bfloat16*)(ws + OFF_KH);
  __hip_bfloat16* vt = (__hip_bfloat16*)(ws + OFF_VT);
  double* inv = (double*)(ws + OFF_INV);
  float* RbZb = (float*)(ws + OFF_RBZB);
  __hip_bfloat16* oat = (__hip_bfloat16*)(ws + OFF_OAT);
  short* o2 = (short*)(ws + OFF_O2);
  short* rx = (short*)(ws + OFF_RX);
  float* Hb = (float*)(ws + OFF_HB);

  float* out0 = (float*)d_out;
  float* out1 = out0 + (size_t)8388608;

  // wt slot order: 0=q 1=k 2=v 3=o 4=xr 5=xz 6=yr 7=yz 8=xg 9=yg
  W10 wargs;
  wargs.p[0] = (const float*)d_in[3];   // Wq
  wargs.p[1] = (const float*)d_in[5];   // Wk
  wargs.p[2] = (const float*)d_in[7];   // Wv
  wargs.p[3] = (const float*)d_in[9];   // Wo
  wargs.p[4] = (const float*)d_in[11];  // Wxr
  wargs.p[5] = (const float*)d_in[15];  // Wxz
  wargs.p[6] = (const float*)d_in[13];  // Wyr
  wargs.p[7] = (const float*)d_in[17];  // Wyz
  wargs.p[8] = (const float*)d_in[19];  // Wxg
  wargs.p[9] = (const float*)d_in[21];  // Wyg

  k_cvtx<<<8192, 256, 0, stream>>>(key_in, xbf);
  k_wt<<<dim3(32, 32, 10), 256, 0, stream>>>(wargs, wt);
  k_tabinv<<<1, 512, 0, stream>>>(inv);
  k_table<<<10000, 256, 0, stream>>>(tab, inv);

  // q/k projections with fused RoPE; v with fused transpose
  k_gemm<1, CM_ROPE><<<dim3(64, 8), 256, 0, stream>>>(
      xbf, wt + (size_t)0 * 1048576, bq, nullptr, (void*)qh, 0, tab, key_index, 9, 512);
  k_gemm<0, CM_ROPE><<<dim3(128, 8), 256, 0, stream>>>(
      xbf, wt + (size_t)1 * 1048576, bk, nullptr, (void*)kh, 0, tab, key_index, 10, 0);
  k_gemm<0, CM_VT><<<dim3(128, 8), 256, 0, stream>>>(
      xbf, wt + (size_t)2 * 1048576, bv, nullptr, (void*)vt, 0, nullptr, nullptr, 0, 0);

  // attention (1D grid, b-major XCD swizzle; mean written directly)
  k_attn<<<dim3(512), 512, 0, stream>>>(qh, kh, vt, pad, out1, oat);

  // output projection + merged gates
  k_gemm<0, CM_BF16><<<dim3(64, 8), 256, 0, stream>>>(
      (const short*)oat, wt + (size_t)3 * 1048576, bo, nullptr, (void*)o2, 1024,
      nullptr, nullptr, 0, 0);
  k_gemm<1, CM_F32><<<dim3(64, 16), 256, 0, stream>>>(
      xbf, wt + (size_t)4 * 1048576, bxr, bxz, (void*)RbZb, 2048,
      nullptr, nullptr, 0, 0);
  k_gemm<0, CM_F32ACC><<<dim3(64, 16), 256, 0, stream>>>(
      o2, wt + (size_t)6 * 1048576, byr, byz, (void*)RbZb, 2048,
      nullptr, nullptr, 0, 0);
  k_rx<<<8192, 256, 0, stream>>>(RbZb, key_in, rx);
  k_gemm<0, CM_F32><<<dim3(64, 8), 256, 0, stream>>>(
      rx, wt + (size_t)8 * 1048576, bxg, nullptr, (void*)Hb, 1024,
      nullptr, nullptr, 0, 0);
  k_gemm<0, CM_F32ACC><<<dim3(64, 8), 256, 0, stream>>>(
      o2, wt + (size_t)9 * 1048576, byg, nullptr, (void*)Hb, 1024,
      nullptr, nullptr, 0, 0);
  k_final<<<8192, 256, 0, stream>>>(RbZb, Hb, key_in, out0);
}